// Round 8
// baseline (1176.112 us; speedup 1.0000x reference)
//
#include <hip/hip_runtime.h>

typedef unsigned short u16;
typedef short s8v __attribute__((ext_vector_type(8)));
typedef float f4v __attribute__((ext_vector_type(4)));

__device__ __forceinline__ float bf2f(u16 s) {
  unsigned u = ((unsigned)s) << 16;
  return __builtin_bit_cast(float, u);
}
__device__ __forceinline__ u16 f2bf(float f) {
  unsigned u = __builtin_bit_cast(unsigned, f);
  unsigned r = u + 0x7fffu + ((u >> 16) & 1u);  // RNE (no NaN here)
  return (u16)(r >> 16);
}
__device__ __forceinline__ s8v load8bf(const u16* p) {
  return __builtin_bit_cast(s8v, *(const uint4*)p);
}
__device__ __forceinline__ f4v mfma16(s8v a, s8v b, f4v c) {
  return __builtin_amdgcn_mfma_f32_16x16x32_bf16(a, b, c, 0, 0, 0);
}
// Pin a 128-bit fragment into registers: asm outputs cannot be rematerialized
// or sunk into the loop, defeating the backend's demote-to-scratch heuristic.
__device__ __forceinline__ s8v pin8(s8v x) {
  union { s8v v; unsigned u[4]; } t;
  t.v = x;
  asm volatile("" : "+v"(t.u[0]), "+v"(t.u[1]), "+v"(t.u[2]), "+v"(t.u[3]));
  return t.v;
}
// LDS-only barrier: __syncthreads() drains vmcnt(0) (global stores/prefetch);
// the scan only needs LDS ordering across the double-buffered images.
__device__ __forceinline__ void barrier_lds() {
  asm volatile("s_waitcnt lgkmcnt(0)\n\ts_barrier" ::: "memory");
}
// 8 consecutive f32 -> bf16 hi + bf16 lo fragments (split precision)
__device__ __forceinline__ void cvt8(const float* p, s8v& hi, s8v& lo) {
  float4 x0 = ((const float4*)p)[0];
  float4 x1 = ((const float4*)p)[1];
  float v[8] = {x0.x, x0.y, x0.z, x0.w, x1.x, x1.y, x1.z, x1.w};
  union { s8v v; u16 a[8]; } H, L;
#pragma unroll
  for (int i = 0; i < 8; ++i) {
    u16 h = f2bf(v[i]);
    H.a[i] = h;
    L.a[i] = f2bf(v[i] - bf2f(h));
  }
  hi = H.v;
  lo = L.v;
}
// tanh(x) = 1 - 2/(1+e^{2x}) via hw exp2/rcp (~1e-6 abs err)
__device__ __forceinline__ float fast_tanh(float x) {
  float t = __builtin_amdgcn_exp2f(x * 2.885390081777927f);
  return 1.f - 2.f * __builtin_amdgcn_rcpf(t + 1.f);
}
__device__ __forceinline__ float fast_sigmoid(float x) {
  float t = __builtin_amdgcn_exp2f(x * -1.4426950408889634f);
  return __builtin_amdgcn_rcpf(1.f + t);
}

// ---------------------------------------------------------------------------
// Prep: g_Whh{0,1} -> bf16 row-major; e-weights -> bf16; GEMM weights ->
// bf16 hi/lo split pairs; mask -> f32 table [s][b].
// ---------------------------------------------------------------------------
__global__ void k_prep(const float* __restrict__ W0, const float* __restrict__ W1,
                       u16* __restrict__ whh0b, u16* __restrict__ whh1b,
                       const float* __restrict__ E0, const float* __restrict__ E1,
                       const float* __restrict__ E2, u16* __restrict__ B0,
                       u16* __restrict__ B1, u16* __restrict__ B2,
                       const float* __restrict__ gW0, u16* __restrict__ gw0hi,
                       u16* __restrict__ gw0lo, const float* __restrict__ gW1,
                       u16* __restrict__ gw1hi, u16* __restrict__ gw1lo,
                       const float* __restrict__ hW, u16* __restrict__ hWhi,
                       u16* __restrict__ hWlo, const float* __restrict__ dW,
                       u16* __restrict__ dWhi, u16* __restrict__ dWlo,
                       const int* __restrict__ mask, float* __restrict__ maskfb) {
  int t = blockIdx.x * 256 + threadIdx.x;  // 598016 total
  if (t < 131072) {
    int layer = t >> 16;
    int idx = t & 65535;
    const float* W = layer ? W1 : W0;
    u16* dst = layer ? whh1b : whh0b;
    dst[idx] = f2bf(W[idx]);
  } else if (t < 327680) {
    int c = t - 131072;
    int which = c >> 16;
    int idx = c & 65535;
    const float* src = which == 0 ? E0 : (which == 1 ? E1 : E2);
    u16* dst = which == 0 ? B0 : (which == 1 ? B1 : B2);
    dst[idx] = f2bf(src[idx]);
  } else if (t < 589824) {
    const float* src;
    u16 *dhi, *dlo;
    int idx;
    if (t < 458752) { idx = t - 327680; src = gW0; dhi = gw0hi; dlo = gw0lo; }
    else if (t < 524288) { idx = t - 458752; src = gW1; dhi = gw1hi; dlo = gw1lo; }
    else if (t < 557056) { idx = t - 524288; src = hW; dhi = hWhi; dlo = hWlo; }
    else { idx = t - 557056; src = dW; dhi = dWhi; dlo = dWlo; }
    float v = src[idx];
    u16 h = f2bf(v);
    dhi[idx] = h;
    dlo[idx] = f2bf(v - bf2f(h));
  } else if (t < 598016) {
    int c = t - 589824;  // c = s*16 + b
    int s = c >> 4, b = c & 15;
    maskfb[c] = (s == 0) ? 1.f : (float)mask[b * 511 + s - 1];
  }
}

// ---------------------------------------------------------------------------
// xw0 = X @ g_Wih0^T + bih0 + bhh0 (split-bf16, pre-split W). grid (128,4)x256.
// ---------------------------------------------------------------------------
__launch_bounds__(256)
__global__ void k_xw0(const float* __restrict__ input, const float* __restrict__ sentinel,
                      const u16* __restrict__ Whi, const u16* __restrict__ Wlo,
                      const float* __restrict__ b1, const float* __restrict__ b2,
                      float* __restrict__ outxw) {
  const int l = threadIdx.x & 63;
  const int wv = threadIdx.x >> 6;
  const int l15 = l & 15, q = l >> 4;
  const int row0 = blockIdx.x * 64 + wv * 16;
  const int col0 = blockIdx.y * 64;
  int row = row0 + l15;
  int s = row & 511, b = row >> 9;
  const float* aptr = (s == 0) ? sentinel : input + (((size_t)(b * 511 + s - 1)) << 9);
  f4v acc[4];
#pragma unroll
  for (int i = 0; i < 4; ++i) acc[i] = (f4v){0.f, 0.f, 0.f, 0.f};
#pragma unroll
  for (int kt = 0; kt < 16; ++kt) {
    int k0 = kt * 32 + q * 8;
    s8v ah, al;
    cvt8(aptr + k0, ah, al);
#pragma unroll
    for (int nt = 0; nt < 4; ++nt) {
      int j = col0 + nt * 16 + l15;
      s8v wh = load8bf(Whi + ((size_t)j << 9) + k0);
      s8v wl = load8bf(Wlo + ((size_t)j << 9) + k0);
      acc[nt] = mfma16(ah, wh, acc[nt]);
      acc[nt] = mfma16(al, wh, acc[nt]);
      acc[nt] = mfma16(ah, wl, acc[nt]);
    }
  }
#pragma unroll
  for (int nt = 0; nt < 4; ++nt) {
    int col = col0 + nt * 16 + l15;
    float bias = b1[col] + b2[col];
#pragma unroll
    for (int r = 0; r < 4; ++r) {
      int rr = row0 + q * 4 + r;
      outxw[((size_t)rr << 8) + col] = acc[nt][r] + bias;
    }
  }
}

// ---------------------------------------------------------------------------
// Generic split-bf16 C = act(A @ W^T + b1 (+b2)); pre-split W hi/lo.
// act=0: identity; act=1: elu. grid (N/64, J/64) x 256.
// ---------------------------------------------------------------------------
__launch_bounds__(256)
__global__ void k_gemm(const float* __restrict__ A, const u16* __restrict__ Whi,
                       const u16* __restrict__ Wlo, const float* __restrict__ b1,
                       const float* __restrict__ b2, float* __restrict__ outf,
                       int K, int J, int act) {
  const int l = threadIdx.x & 63;
  const int wv = threadIdx.x >> 6;
  const int l15 = l & 15, q = l >> 4;
  const int row0 = blockIdx.x * 64 + wv * 16;
  const int col0 = blockIdx.y * 64;
  const float* aptr = A + (size_t)(row0 + l15) * K;
  f4v acc[4];
#pragma unroll
  for (int i = 0; i < 4; ++i) acc[i] = (f4v){0.f, 0.f, 0.f, 0.f};
  const int nkt = K >> 5;
  for (int kt = 0; kt < nkt; ++kt) {
    int k0 = kt * 32 + q * 8;
    s8v ah, al;
    cvt8(aptr + k0, ah, al);
#pragma unroll
    for (int nt = 0; nt < 4; ++nt) {
      int j = col0 + nt * 16 + l15;
      s8v wh = load8bf(Whi + (size_t)j * K + k0);
      s8v wl = load8bf(Wlo + (size_t)j * K + k0);
      acc[nt] = mfma16(ah, wh, acc[nt]);
      acc[nt] = mfma16(al, wh, acc[nt]);
      acc[nt] = mfma16(ah, wl, acc[nt]);
    }
  }
#pragma unroll
  for (int nt = 0; nt < 4; ++nt) {
    int col = col0 + nt * 16 + l15;
    float bias = b1[col] + (b2 ? b2[col] : 0.f);
#pragma unroll
    for (int r = 0; r < 4; ++r) {
      int rr = row0 + q * 4 + r;
      float v = acc[nt][r] + bias;
      if (act) v = v > 0.f ? v : (__builtin_amdgcn_exp2f(v * 1.4426950408889634f) - 1.f);
      outf[(size_t)rr * J + col] = v;
    }
  }
}

// ---------------------------------------------------------------------------
// FUSED two-layer MFMA RNN scan: 16 wgs (one per batch row), 256 thr = 4
// waves (1/SIMD, 512-VGPR budget). Software pipeline, one barrier per step:
//   step g: h1[g]   = tanh(xw1[g] + Whh0·h1[g-1])       (rec1)
//           xw2[g-1]= Wih1·h1[g-1] + bias2              (same LDS reads!)
//           h2[g-2] = tanh(xw2[g-2] + Whh1·h2[g-3])     (rec2) -> gs out
// Wave wv owns cols [wv*64,+64) of ALL THREE matvecs: 384 pinned VGPRs.
// A-operand = h broadcast to all 16 M-rows (same-address ds_read); per-lane
// scalars injected via C-reg0 trick (acc[nt][0] += per-col scalar).
// ---------------------------------------------------------------------------
__launch_bounds__(256, 1)
__global__ void k_scan_f(const float* __restrict__ xw, const u16* __restrict__ W0b,
                         const u16* __restrict__ Wxb, const u16* __restrict__ W1b,
                         const float* __restrict__ bih1, const float* __restrict__ bhh1,
                         float* __restrict__ outf, const float* __restrict__ maskf) {
  __shared__ u16 H1[2][272];
  __shared__ u16 H2[2][272];
  __shared__ float XW2[2][272];
  __shared__ float mtab[512];
  const int tid = threadIdx.x;
  const int l = tid & 63, wv = tid >> 6;  // wv 0..3
  const int l15 = l & 15, q = l >> 4;
  const int b = blockIdx.x;  // batch row

  // pinned stationary weights: rows j = wv*64 + nt*16 + l15
  s8v w0[4][8], wx[4][8], w1[4][8];
#pragma unroll
  for (int nt = 0; nt < 4; ++nt) {
    int j = wv * 64 + nt * 16 + l15;
#pragma unroll
    for (int kt = 0; kt < 8; ++kt) {
      int off = (j << 8) + kt * 32 + q * 8;
      w0[nt][kt] = pin8(load8bf(W0b + off));
      wx[nt][kt] = pin8(load8bf(Wxb + off));
      w1[nt][kt] = pin8(load8bf(W1b + off));
    }
  }
  if (tid < 256) {
    H1[0][tid] = 0; H1[1][tid] = 0;
    H2[0][tid] = 0; H2[1][tid] = 0;
    XW2[0][tid] = 0.f; XW2[1][tid] = 0.f;
  }
  for (int c = tid; c < 512; c += 256) mtab[c] = maskf[c * 16 + b];

  const int j0 = wv * 64 + l15;  // + nt*16
  float b2v[4];
#pragma unroll
  for (int nt = 0; nt < 4; ++nt) b2v[nt] = bih1[j0 + nt * 16] + bhh1[j0 + nt * 16];
  __syncthreads();

  const size_t nbase = (size_t)b << 9;
  const float* xrow = xw + (nbase << 8);
  const int q0 = (q == 0);

  float xA[4], xB[4];
#pragma unroll
  for (int nt = 0; nt < 4; ++nt) {
    xA[nt] = xrow[j0 + nt * 16];
    xB[nt] = xrow[256 + j0 + nt * 16];
  }

  auto STEP = [&](int g, int par, float* xc) {
    const u16* H1r = &H1[par][0];
    const u16* H2r = &H2[par][0];
    // per-lane scalar injections via C-reg0
    f4v a1[4], ax[4], a2[4];
#pragma unroll
    for (int nt = 0; nt < 4; ++nt) {
      a1[nt] = (f4v){xc[nt], 0.f, 0.f, 0.f};
      ax[nt] = (f4v){b2v[nt], 0.f, 0.f, 0.f};
      a2[nt] = (f4v){XW2[par][j0 + nt * 16], 0.f, 0.f, 0.f};
    }
#pragma unroll
    for (int kt = 0; kt < 8; ++kt) {
      s8v h1b = load8bf(H1r + kt * 32 + q * 8);  // broadcast read, shared by rec1+xw2
#pragma unroll
      for (int nt = 0; nt < 4; ++nt) {
        a1[nt] = mfma16(h1b, w0[nt][kt], a1[nt]);
        ax[nt] = mfma16(h1b, wx[nt][kt], ax[nt]);
      }
    }
#pragma unroll
    for (int kt = 0; kt < 8; ++kt) {
      s8v h2b = load8bf(H2r + kt * 32 + q * 8);
#pragma unroll
      for (int nt = 0; nt < 4; ++nt) a2[nt] = mfma16(h2b, w1[nt][kt], a2[nt]);
    }
    // L1 epilogue: h1[g]
    if (g < 512) {
      u16* Hw = &H1[1 - par][0];
#pragma unroll
      for (int nt = 0; nt < 4; ++nt) {
        float h = fast_tanh(a1[nt][0]);
        if (q0) Hw[j0 + nt * 16] = f2bf(h);
      }
    }
    // xw2[g-1]
    if (g >= 1 && g < 513) {
      float* Xw = &XW2[1 - par][0];
#pragma unroll
      for (int nt = 0; nt < 4; ++nt)
        if (q0) Xw[j0 + nt * 16] = ax[nt][0];
    }
    // L2 epilogue: h2[g-2] -> gs out
    if (g >= 2) {
      int t = g - 2;
      float mf = mtab[t];
      u16* Hw = &H2[1 - par][0];
      float* orow = outf + ((nbase + t) << 8);
#pragma unroll
      for (int nt = 0; nt < 4; ++nt) {
        float h = fast_tanh(a2[nt][0]);
        if (q0) {
          Hw[j0 + nt * 16] = f2bf(h);
          orow[j0 + nt * 16] = h * mf;
        }
      }
    }
  };

  for (int g = 0; g < 514; g += 2) {
    STEP(g, 0, xA);
    int sp = g + 2; if (sp > 511) sp = 511;
#pragma unroll
    for (int nt = 0; nt < 4; ++nt) xA[nt] = xrow[(sp << 8) + j0 + nt * 16];
    barrier_lds();
    STEP(g + 1, 1, xB);
    int sq = g + 3; if (sq > 511) sq = 511;
#pragma unroll
    for (int nt = 0; nt < 4; ++nt) xB[nt] = xrow[(sq << 8) + j0 + nt * 16];
    barrier_lds();
  }
}

// ---------------------------------------------------------------------------
// Encoder: 32 steps, 32 rows/wg, 512 threads = 8 waves; weights resident;
// h0/h1 bf16 in LDS.
// ---------------------------------------------------------------------------
__launch_bounds__(512, 2)
__global__ void k_enc(const float* __restrict__ gs,
                      const u16* __restrict__ W0b, const u16* __restrict__ W1b,
                      const u16* __restrict__ W2b, const float* __restrict__ wih0,
                      const float* __restrict__ bih0, const float* __restrict__ bhh0,
                      const float* __restrict__ bih1, const float* __restrict__ bhh1,
                      const float* __restrict__ clsW, const float* __restrict__ clsb,
                      float* __restrict__ Ab) {
  __shared__ __align__(16) u16 hA0[32 * 264];
  __shared__ __align__(16) u16 hA1[32 * 264];
  __shared__ float xe[32];
  __shared__ float b0v[256], w0v[256], b1v[256], clsv[256];
  __shared__ float clsbs;
  const int tid = threadIdx.x;
  const int n0 = blockIdx.x * 32;

  for (int c = tid; c < 8192; c += 512) {
    int row = c >> 8, col = c & 255;
    hA0[row * 264 + col] = f2bf(gs[(((size_t)(n0 + row)) << 8) + col]);
    hA1[row * 264 + col] = 0;
  }
  if (tid < 256) {
    b0v[tid] = bih0[tid] + bhh0[tid];
    w0v[tid] = wih0[tid];
    b1v[tid] = bih1[tid] + bhh1[tid];
    clsv[tid] = clsW[tid];
  }
  if (tid < 32) xe[tid] = 1.0f;
  if (tid == 0) clsbs = clsb[0];

  const int l = tid & 63, wv = tid >> 6;
  const int l15 = l & 15, q = l >> 4;
  const int colbase = wv * 32;

  s8v w0[2][8], w1[2][8], w2[2][8];
#pragma unroll
  for (int nt = 0; nt < 2; ++nt) {
    int jj = colbase + nt * 16 + l15;
#pragma unroll
    for (int kt = 0; kt < 8; ++kt) {
      int off = (jj << 8) + kt * 32 + q * 8;
      w0[nt][kt] = load8bf(W0b + off);
      w1[nt][kt] = load8bf(W1b + off);
      w2[nt][kt] = load8bf(W2b + off);
    }
  }
  __syncthreads();

  for (int m = 0; m < 32; ++m) {
    f4v acc[2][2];
#pragma unroll
    for (int mt = 0; mt < 2; ++mt)
#pragma unroll
      for (int nt = 0; nt < 2; ++nt) acc[mt][nt] = (f4v){0.f, 0.f, 0.f, 0.f};
#pragma unroll
    for (int kt = 0; kt < 8; ++kt) {
#pragma unroll
      for (int mt = 0; mt < 2; ++mt) {
        s8v a = __builtin_bit_cast(s8v, *(const uint4*)&hA0[(mt * 16 + l15) * 264 + kt * 32 + q * 8]);
        acc[mt][0] = mfma16(a, w0[0][kt], acc[mt][0]);
        acc[mt][1] = mfma16(a, w0[1][kt], acc[mt][1]);
      }
    }
    __syncthreads();
#pragma unroll
    for (int nt = 0; nt < 2; ++nt) {
      int col = colbase + nt * 16 + l15;
      float wc = w0v[col], bc = b0v[col];
#pragma unroll
      for (int mt = 0; mt < 2; ++mt)
#pragma unroll
        for (int r = 0; r < 4; ++r) {
          int row = mt * 16 + q * 4 + r;
          float v = acc[mt][nt][r] + xe[row] * wc + bc;
          hA0[row * 264 + col] = f2bf(fast_tanh(v));
        }
    }
    __syncthreads();
#pragma unroll
    for (int mt = 0; mt < 2; ++mt)
#pragma unroll
      for (int nt = 0; nt < 2; ++nt) acc[mt][nt] = (f4v){0.f, 0.f, 0.f, 0.f};
#pragma unroll
    for (int kt = 0; kt < 8; ++kt) {
#pragma unroll
      for (int mt = 0; mt < 2; ++mt) {
        s8v a0 = __builtin_bit_cast(s8v, *(const uint4*)&hA0[(mt * 16 + l15) * 264 + kt * 32 + q * 8]);
        s8v a1 = __builtin_bit_cast(s8v, *(const uint4*)&hA1[(mt * 16 + l15) * 264 + kt * 32 + q * 8]);
        acc[mt][0] = mfma16(a0, w1[0][kt], acc[mt][0]);
        acc[mt][1] = mfma16(a0, w1[1][kt], acc[mt][1]);
        acc[mt][0] = mfma16(a1, w2[0][kt], acc[mt][0]);
        acc[mt][1] = mfma16(a1, w2[1][kt], acc[mt][1]);
      }
    }
    __syncthreads();
#pragma unroll
    for (int nt = 0; nt < 2; ++nt) {
      int col = colbase + nt * 16 + l15;
      float bc = b1v[col];
#pragma unroll
      for (int mt = 0; mt < 2; ++mt)
#pragma unroll
        for (int r = 0; r < 4; ++r) {
          int row = mt * 16 + q * 4 + r;
          float v = acc[mt][nt][r] + bc;
          hA1[row * 264 + col] = f2bf(fast_tanh(v));
        }
    }
    __syncthreads();
    if (tid < 256) {
      int row = tid >> 3, seg = tid & 7;
      float sum = 0.f;
#pragma unroll
      for (int u = 0; u < 4; ++u) {
        int col = seg * 32 + u * 8;
#pragma unroll
        for (int e = 0; e < 8; ++e) sum += bf2f(hA1[row * 264 + col + e]) * clsv[col + e];
      }
      sum += __shfl_down(sum, 4, 8);
      sum += __shfl_down(sum, 2, 8);
      sum += __shfl_down(sum, 1, 8);
      if (seg == 0) {
        float pp = fast_sigmoid(sum + clsbs);
        xe[row] = pp;
        Ab[(((size_t)(n0 + row)) << 5) + m] = pp;
      }
    }
    __syncthreads();
  }
}

// ---------------------------------------------------------------------------
// arc_logits[b][j][i] = (j>=max(0,i-32) && j<i) ? Ab[(b*512+i)*32 + j-start] : 0
// ---------------------------------------------------------------------------
__global__ void k_arc(const float* __restrict__ Ab, float* __restrict__ out2) {
  int t = blockIdx.x * 256 + threadIdx.x;  // 4194304 total
  int b = t >> 18;
  int rem = t & 262143;
  int j = rem >> 9, i = rem & 511;
  int start = i - 32;
  if (start < 0) start = 0;
  float v = 0.f;
  if (j >= start && j < i) v = Ab[((((size_t)b << 9) + i) << 5) + (j - start)];
  out2[t] = v;
}

// ---------------------------------------------------------------------------
extern "C" void kernel_launch(void* const* d_in, const int* in_sizes, int n_in,
                              void* d_out, int out_size, void* d_ws, size_t ws_size,
                              hipStream_t stream) {
  const float* input    = (const float*)d_in[0];
  const float* sentinel = (const float*)d_in[1];
  const float* g_Wih0   = (const float*)d_in[2];
  const float* g_Whh0   = (const float*)d_in[3];
  const float* g_bih0   = (const float*)d_in[4];
  const float* g_bhh0   = (const float*)d_in[5];
  const float* g_Wih1   = (const float*)d_in[6];
  const float* g_Whh1   = (const float*)d_in[7];
  const float* g_bih1   = (const float*)d_in[8];
  const float* g_bhh1   = (const float*)d_in[9];
  const float* e_Wih0   = (const float*)d_in[10];
  const float* e_Whh0   = (const float*)d_in[11];
  const float* e_bih0   = (const float*)d_in[12];
  const float* e_bhh0   = (const float*)d_in[13];
  const float* e_Wih1   = (const float*)d_in[14];
  const float* e_Whh1   = (const float*)d_in[15];
  const float* e_bih1   = (const float*)d_in[16];
  const float* e_bhh1   = (const float*)d_in[17];
  const float* cls_W    = (const float*)d_in[18];
  const float* cls_b    = (const float*)d_in[19];
  const float* head_W   = (const float*)d_in[20];
  const float* head_b   = (const float*)d_in[21];
  const float* dep_W    = (const float*)d_in[22];
  const float* dep_b    = (const float*)d_in[23];
  const int* mask       = (const int*)d_in[24];

  float* out = (float*)d_out;
  char* ws = (char*)d_ws;
  float* xw_buf = (float*)ws;                                  // 8 MB
  float* gsb    = (float*)(ws + (16u << 20));                  // 8 MB
  float* Ab     = (float*)(ws + (24u << 20));                  // 1 MB
  size_t o = (25u << 20);
  u16* whh0b   = (u16*)(ws + o); o += 128u << 10;
  u16* whh1b   = (u16*)(ws + o); o += 128u << 10;
  float* maskfb= (float*)(ws + o); o += 32u << 10;
  u16* eb0     = (u16*)(ws + o); o += 128u << 10;
  u16* eb1     = (u16*)(ws + o); o += 128u << 10;
  u16* eb2     = (u16*)(ws + o); o += 128u << 10;
  u16* gw0hi   = (u16*)(ws + o); o += 256u << 10;
  u16* gw0lo   = (u16*)(ws + o); o += 256u << 10;
  u16* gw1hi   = (u16*)(ws + o); o += 128u << 10;
  u16* gw1lo   = (u16*)(ws + o); o += 128u << 10;
  u16* hWhi    = (u16*)(ws + o); o += 64u << 10;
  u16* hWlo    = (u16*)(ws + o); o += 64u << 10;
  u16* dWhi    = (u16*)(ws + o); o += 64u << 10;
  u16* dWlo    = (u16*)(ws + o); o += 64u << 10;

  k_prep<<<2336, 256, 0, stream>>>(g_Whh0, g_Whh1, whh0b, whh1b, e_Whh0, e_Wih1, e_Whh1,
                                   eb0, eb1, eb2, g_Wih0, gw0hi, gw0lo, g_Wih1, gw1hi,
                                   gw1lo, head_W, hWhi, hWlo, dep_W, dWhi, dWlo,
                                   mask, maskfb);
  k_xw0<<<dim3(128, 4), 256, 0, stream>>>(input, sentinel, gw0hi, gw0lo, g_bih0, g_bhh0,
                                          xw_buf);
  k_scan_f<<<16, 256, 0, stream>>>(xw_buf, whh0b, gw1hi, whh1b, g_bih1, g_bhh1,
                                   gsb, maskfb);
  k_gemm<<<dim3(128, 2), 256, 0, stream>>>(gsb, hWhi, hWlo, head_b, nullptr, out,
                                           256, 128, 1);
  k_gemm<<<dim3(128, 2), 256, 0, stream>>>(gsb, dWhi, dWlo, dep_b, nullptr, out + 1048576,
                                           256, 128, 1);
  k_enc<<<256, 512, 0, stream>>>(gsb, eb0, eb1, eb2, e_Wih0, e_bih0, e_bhh0,
                                 e_bih1, e_bhh1, cls_W, cls_b, Ab);
  k_arc<<<16384, 256, 0, stream>>>(Ab, out + 2097152);
}

// Round 9
// 852.608 us; speedup vs baseline: 1.3794x; 1.3794x over previous
//
#include <hip/hip_runtime.h>

typedef unsigned short u16;
typedef short s8v __attribute__((ext_vector_type(8)));
typedef float f4v __attribute__((ext_vector_type(4)));

__device__ __forceinline__ float bf2f(u16 s) {
  unsigned u = ((unsigned)s) << 16;
  return __builtin_bit_cast(float, u);
}
__device__ __forceinline__ u16 f2bf(float f) {
  unsigned u = __builtin_bit_cast(unsigned, f);
  unsigned r = u + 0x7fffu + ((u >> 16) & 1u);  // RNE (no NaN here)
  return (u16)(r >> 16);
}
__device__ __forceinline__ s8v load8bf(const u16* p) {
  return __builtin_bit_cast(s8v, *(const uint4*)p);
}
__device__ __forceinline__ f4v mfma16(s8v a, s8v b, f4v c) {
  return __builtin_amdgcn_mfma_f32_16x16x32_bf16(a, b, c, 0, 0, 0);
}
// Pin a 128-bit fragment into registers: prevents remat/sink of the load.
// NOTE (R8 lesson): pinning does NOT prevent spill if demand > VGPR cap —
// the design must fit under the budget (here: 192 weight VGPRs @ 256 cap).
__device__ __forceinline__ s8v pin8(s8v x) {
  union { s8v v; unsigned u[4]; } t;
  t.v = x;
  asm volatile("" : "+v"(t.u[0]), "+v"(t.u[1]), "+v"(t.u[2]), "+v"(t.u[3]));
  return t.v;
}
// LDS-only barrier: __syncthreads() drains vmcnt(0) (global stores/prefetch);
// the scan only needs LDS ordering across the double-buffered images.
__device__ __forceinline__ void barrier_lds() {
  asm volatile("s_waitcnt lgkmcnt(0)\n\ts_barrier" ::: "memory");
}
// 8 consecutive f32 -> bf16 hi + bf16 lo fragments (split precision)
__device__ __forceinline__ void cvt8(const float* p, s8v& hi, s8v& lo) {
  float4 x0 = ((const float4*)p)[0];
  float4 x1 = ((const float4*)p)[1];
  float v[8] = {x0.x, x0.y, x0.z, x0.w, x1.x, x1.y, x1.z, x1.w};
  union { s8v v; u16 a[8]; } H, L;
#pragma unroll
  for (int i = 0; i < 8; ++i) {
    u16 h = f2bf(v[i]);
    H.a[i] = h;
    L.a[i] = f2bf(v[i] - bf2f(h));
  }
  hi = H.v;
  lo = L.v;
}
// tanh(x) = 1 - 2/(1+e^{2x}) via hw exp2/rcp (~1e-6 abs err)
__device__ __forceinline__ float fast_tanh(float x) {
  float t = __builtin_amdgcn_exp2f(x * 2.885390081777927f);
  return 1.f - 2.f * __builtin_amdgcn_rcpf(t + 1.f);
}
__device__ __forceinline__ float fast_sigmoid(float x) {
  float t = __builtin_amdgcn_exp2f(x * -1.4426950408889634f);
  return __builtin_amdgcn_rcpf(1.f + t);
}

// ---------------------------------------------------------------------------
// Prep: g_Whh{0,1} -> bf16 row-major; e-weights -> bf16; GEMM weights ->
// bf16 hi/lo split pairs; mask -> f32 table [s][b].
// ---------------------------------------------------------------------------
__global__ void k_prep(const float* __restrict__ W0, const float* __restrict__ W1,
                       u16* __restrict__ whh0b, u16* __restrict__ whh1b,
                       const float* __restrict__ E0, const float* __restrict__ E1,
                       const float* __restrict__ E2, u16* __restrict__ B0,
                       u16* __restrict__ B1, u16* __restrict__ B2,
                       const float* __restrict__ gW0, u16* __restrict__ gw0hi,
                       u16* __restrict__ gw0lo, const float* __restrict__ gW1,
                       u16* __restrict__ gw1hi, u16* __restrict__ gw1lo,
                       const float* __restrict__ hW, u16* __restrict__ hWhi,
                       u16* __restrict__ hWlo, const float* __restrict__ dW,
                       u16* __restrict__ dWhi, u16* __restrict__ dWlo,
                       const int* __restrict__ mask, float* __restrict__ maskfb) {
  int t = blockIdx.x * 256 + threadIdx.x;  // 598016 total
  if (t < 131072) {
    int layer = t >> 16;
    int idx = t & 65535;
    const float* W = layer ? W1 : W0;
    u16* dst = layer ? whh1b : whh0b;
    dst[idx] = f2bf(W[idx]);
  } else if (t < 327680) {
    int c = t - 131072;
    int which = c >> 16;
    int idx = c & 65535;
    const float* src = which == 0 ? E0 : (which == 1 ? E1 : E2);
    u16* dst = which == 0 ? B0 : (which == 1 ? B1 : B2);
    dst[idx] = f2bf(src[idx]);
  } else if (t < 589824) {
    const float* src;
    u16 *dhi, *dlo;
    int idx;
    if (t < 458752) { idx = t - 327680; src = gW0; dhi = gw0hi; dlo = gw0lo; }
    else if (t < 524288) { idx = t - 458752; src = gW1; dhi = gw1hi; dlo = gw1lo; }
    else if (t < 557056) { idx = t - 524288; src = hW; dhi = hWhi; dlo = hWlo; }
    else { idx = t - 557056; src = dW; dhi = dWhi; dlo = dWlo; }
    float v = src[idx];
    u16 h = f2bf(v);
    dhi[idx] = h;
    dlo[idx] = f2bf(v - bf2f(h));
  } else if (t < 598016) {
    int c = t - 589824;  // c = s*16 + b
    int s = c >> 4, b = c & 15;
    maskfb[c] = (s == 0) ? 1.f : (float)mask[b * 511 + s - 1];
  }
}

// ---------------------------------------------------------------------------
// xw0 = X @ g_Wih0^T + bih0 + bhh0 (split-bf16, pre-split W). grid (128,4)x256.
// ---------------------------------------------------------------------------
__launch_bounds__(256)
__global__ void k_xw0(const float* __restrict__ input, const float* __restrict__ sentinel,
                      const u16* __restrict__ Whi, const u16* __restrict__ Wlo,
                      const float* __restrict__ b1, const float* __restrict__ b2,
                      float* __restrict__ outxw) {
  const int l = threadIdx.x & 63;
  const int wv = threadIdx.x >> 6;
  const int l15 = l & 15, q = l >> 4;
  const int row0 = blockIdx.x * 64 + wv * 16;
  const int col0 = blockIdx.y * 64;
  int row = row0 + l15;
  int s = row & 511, b = row >> 9;
  const float* aptr = (s == 0) ? sentinel : input + (((size_t)(b * 511 + s - 1)) << 9);
  f4v acc[4];
#pragma unroll
  for (int i = 0; i < 4; ++i) acc[i] = (f4v){0.f, 0.f, 0.f, 0.f};
#pragma unroll
  for (int kt = 0; kt < 16; ++kt) {
    int k0 = kt * 32 + q * 8;
    s8v ah, al;
    cvt8(aptr + k0, ah, al);
#pragma unroll
    for (int nt = 0; nt < 4; ++nt) {
      int j = col0 + nt * 16 + l15;
      s8v wh = load8bf(Whi + ((size_t)j << 9) + k0);
      s8v wl = load8bf(Wlo + ((size_t)j << 9) + k0);
      acc[nt] = mfma16(ah, wh, acc[nt]);
      acc[nt] = mfma16(al, wh, acc[nt]);
      acc[nt] = mfma16(ah, wl, acc[nt]);
    }
  }
#pragma unroll
  for (int nt = 0; nt < 4; ++nt) {
    int col = col0 + nt * 16 + l15;
    float bias = b1[col] + b2[col];
#pragma unroll
    for (int r = 0; r < 4; ++r) {
      int rr = row0 + q * 4 + r;
      outxw[((size_t)rr << 8) + col] = acc[nt][r] + bias;
    }
  }
}

// ---------------------------------------------------------------------------
// Generic split-bf16 C = act(A @ W^T + b1 (+b2)); pre-split W hi/lo.
// act=0: identity; act=1: elu. grid (N/64, J/64) x 256.
// ---------------------------------------------------------------------------
__launch_bounds__(256)
__global__ void k_gemm(const float* __restrict__ A, const u16* __restrict__ Whi,
                       const u16* __restrict__ Wlo, const float* __restrict__ b1,
                       const float* __restrict__ b2, float* __restrict__ outf,
                       int K, int J, int act) {
  const int l = threadIdx.x & 63;
  const int wv = threadIdx.x >> 6;
  const int l15 = l & 15, q = l >> 4;
  const int row0 = blockIdx.x * 64 + wv * 16;
  const int col0 = blockIdx.y * 64;
  const float* aptr = A + (size_t)(row0 + l15) * K;
  f4v acc[4];
#pragma unroll
  for (int i = 0; i < 4; ++i) acc[i] = (f4v){0.f, 0.f, 0.f, 0.f};
  const int nkt = K >> 5;
  for (int kt = 0; kt < nkt; ++kt) {
    int k0 = kt * 32 + q * 8;
    s8v ah, al;
    cvt8(aptr + k0, ah, al);
#pragma unroll
    for (int nt = 0; nt < 4; ++nt) {
      int j = col0 + nt * 16 + l15;
      s8v wh = load8bf(Whi + (size_t)j * K + k0);
      s8v wl = load8bf(Wlo + (size_t)j * K + k0);
      acc[nt] = mfma16(ah, wh, acc[nt]);
      acc[nt] = mfma16(al, wh, acc[nt]);
      acc[nt] = mfma16(ah, wl, acc[nt]);
    }
  }
#pragma unroll
  for (int nt = 0; nt < 4; ++nt) {
    int col = col0 + nt * 16 + l15;
    float bias = b1[col] + (b2 ? b2[col] : 0.f);
#pragma unroll
    for (int r = 0; r < 4; ++r) {
      int rr = row0 + q * 4 + r;
      float v = acc[nt][r] + bias;
      if (act) v = v > 0.f ? v : (__builtin_amdgcn_exp2f(v * 1.4426950408889634f) - 1.f);
      outf[(size_t)rr * J + col] = v;
    }
  }
}

// ---------------------------------------------------------------------------
// FUSED two-layer MFMA RNN scan v2: 16 wgs (one per batch row), 512 thr =
// 8 waves (2/SIMD, 256-VGPR cap). Wave wv owns cols [wv*32,+32) of ALL THREE
// matvecs -> 192 pinned weight VGPRs/thread (fits: no spill, unlike R8's 384).
// Software pipeline, one barrier per step:
//   step g: h1[g]   = tanh(xw1[g] + Whh0·h1[g-1])       (rec1)
//           xw2[g-1]= Wih1·h1[g-1] + bias2              (same LDS reads!)
//           h2[g-2] = tanh(xw2[g-2] + Whh1·h2[g-3])     (rec2) -> gs out
// A-operand = h broadcast to all 16 M-rows (same-address ds_read); per-lane
// scalars injected via C-reg0 trick.
// ---------------------------------------------------------------------------
__launch_bounds__(512, 2)
__global__ void k_scan_f(const float* __restrict__ xw, const u16* __restrict__ W0b,
                         const u16* __restrict__ Wxb, const u16* __restrict__ W1b,
                         const float* __restrict__ bih1, const float* __restrict__ bhh1,
                         float* __restrict__ outf, const float* __restrict__ maskf) {
  __shared__ u16 H1[2][272];
  __shared__ u16 H2[2][272];
  __shared__ float XW2[2][272];
  __shared__ float mtab[512];
  const int tid = threadIdx.x;
  const int l = tid & 63, wv = tid >> 6;  // wv 0..7
  const int l15 = l & 15, q = l >> 4;
  const int b = blockIdx.x;  // batch row

  // pinned stationary weights: rows j = wv*32 + nt*16 + l15 (nt in {0,1})
  s8v w0[2][8], wx[2][8], w1[2][8];
#pragma unroll
  for (int nt = 0; nt < 2; ++nt) {
    int j = wv * 32 + nt * 16 + l15;
#pragma unroll
    for (int kt = 0; kt < 8; ++kt) {
      int off = (j << 8) + kt * 32 + q * 8;
      w0[nt][kt] = pin8(load8bf(W0b + off));
      wx[nt][kt] = pin8(load8bf(Wxb + off));
      w1[nt][kt] = pin8(load8bf(W1b + off));
    }
  }
  if (tid < 256) {
    H1[0][tid] = 0; H1[1][tid] = 0;
    H2[0][tid] = 0; H2[1][tid] = 0;
    XW2[0][tid] = 0.f; XW2[1][tid] = 0.f;
  }
  if (tid < 512) mtab[tid] = maskf[tid * 16 + b];

  const int j0 = wv * 32 + l15;  // + nt*16
  float b2v[2];
#pragma unroll
  for (int nt = 0; nt < 2; ++nt) b2v[nt] = bih1[j0 + nt * 16] + bhh1[j0 + nt * 16];
  __syncthreads();

  const size_t nbase = (size_t)b << 9;
  const float* xrow = xw + (nbase << 8);
  const int q0 = (q == 0);

  float xA[2], xB[2];
#pragma unroll
  for (int nt = 0; nt < 2; ++nt) {
    xA[nt] = xrow[j0 + nt * 16];
    xB[nt] = xrow[256 + j0 + nt * 16];
  }

  auto STEP = [&](int g, int par, float* xc) {
    const u16* H1r = &H1[par][0];
    const u16* H2r = &H2[par][0];
    // per-lane scalar injections via C-reg0
    f4v a1[2], ax[2], a2[2];
#pragma unroll
    for (int nt = 0; nt < 2; ++nt) {
      a1[nt] = (f4v){xc[nt], 0.f, 0.f, 0.f};
      ax[nt] = (f4v){b2v[nt], 0.f, 0.f, 0.f};
      a2[nt] = (f4v){XW2[par][j0 + nt * 16], 0.f, 0.f, 0.f};
    }
#pragma unroll
    for (int kt = 0; kt < 8; ++kt) {
      s8v h1b = load8bf(H1r + kt * 32 + q * 8);  // broadcast read, shared rec1+xw2
#pragma unroll
      for (int nt = 0; nt < 2; ++nt) {
        a1[nt] = mfma16(h1b, w0[nt][kt], a1[nt]);
        ax[nt] = mfma16(h1b, wx[nt][kt], ax[nt]);
      }
    }
#pragma unroll
    for (int kt = 0; kt < 8; ++kt) {
      s8v h2b = load8bf(H2r + kt * 32 + q * 8);
#pragma unroll
      for (int nt = 0; nt < 2; ++nt) a2[nt] = mfma16(h2b, w1[nt][kt], a2[nt]);
    }
    // L1 epilogue: h1[g]
    if (g < 512) {
      u16* Hw = &H1[1 - par][0];
#pragma unroll
      for (int nt = 0; nt < 2; ++nt) {
        float h = fast_tanh(a1[nt][0]);
        if (q0) Hw[j0 + nt * 16] = f2bf(h);
      }
    }
    // xw2[g-1]
    if (g >= 1 && g < 513) {
      float* Xw = &XW2[1 - par][0];
#pragma unroll
      for (int nt = 0; nt < 2; ++nt)
        if (q0) Xw[j0 + nt * 16] = ax[nt][0];
    }
    // L2 epilogue: h2[g-2] -> gs out
    if (g >= 2) {
      int t = g - 2;
      float mf = mtab[t];
      u16* Hw = &H2[1 - par][0];
      float* orow = outf + ((nbase + t) << 8);
#pragma unroll
      for (int nt = 0; nt < 2; ++nt) {
        float h = fast_tanh(a2[nt][0]);
        if (q0) {
          Hw[j0 + nt * 16] = f2bf(h);
          orow[j0 + nt * 16] = h * mf;
        }
      }
    }
  };

  for (int g = 0; g < 514; g += 2) {
    STEP(g, 0, xA);
    int sp = g + 2; if (sp > 511) sp = 511;
#pragma unroll
    for (int nt = 0; nt < 2; ++nt) xA[nt] = xrow[(sp << 8) + j0 + nt * 16];
    barrier_lds();
    STEP(g + 1, 1, xB);
    int sq = g + 3; if (sq > 511) sq = 511;
#pragma unroll
    for (int nt = 0; nt < 2; ++nt) xB[nt] = xrow[(sq << 8) + j0 + nt * 16];
    barrier_lds();
  }
}

// ---------------------------------------------------------------------------
// Encoder: 32 steps, 32 rows/wg, 512 threads = 8 waves; weights resident;
// h0/h1 bf16 in LDS.
// ---------------------------------------------------------------------------
__launch_bounds__(512, 2)
__global__ void k_enc(const float* __restrict__ gs,
                      const u16* __restrict__ W0b, const u16* __restrict__ W1b,
                      const u16* __restrict__ W2b, const float* __restrict__ wih0,
                      const float* __restrict__ bih0, const float* __restrict__ bhh0,
                      const float* __restrict__ bih1, const float* __restrict__ bhh1,
                      const float* __restrict__ clsW, const float* __restrict__ clsb,
                      float* __restrict__ Ab) {
  __shared__ __align__(16) u16 hA0[32 * 264];
  __shared__ __align__(16) u16 hA1[32 * 264];
  __shared__ float xe[32];
  __shared__ float b0v[256], w0v[256], b1v[256], clsv[256];
  __shared__ float clsbs;
  const int tid = threadIdx.x;
  const int n0 = blockIdx.x * 32;

  for (int c = tid; c < 8192; c += 512) {
    int row = c >> 8, col = c & 255;
    hA0[row * 264 + col] = f2bf(gs[(((size_t)(n0 + row)) << 8) + col]);
    hA1[row * 264 + col] = 0;
  }
  if (tid < 256) {
    b0v[tid] = bih0[tid] + bhh0[tid];
    w0v[tid] = wih0[tid];
    b1v[tid] = bih1[tid] + bhh1[tid];
    clsv[tid] = clsW[tid];
  }
  if (tid < 32) xe[tid] = 1.0f;
  if (tid == 0) clsbs = clsb[0];

  const int l = tid & 63, wv = tid >> 6;
  const int l15 = l & 15, q = l >> 4;
  const int colbase = wv * 32;

  s8v w0[2][8], w1[2][8], w2[2][8];
#pragma unroll
  for (int nt = 0; nt < 2; ++nt) {
    int jj = colbase + nt * 16 + l15;
#pragma unroll
    for (int kt = 0; kt < 8; ++kt) {
      int off = (jj << 8) + kt * 32 + q * 8;
      w0[nt][kt] = load8bf(W0b + off);
      w1[nt][kt] = load8bf(W1b + off);
      w2[nt][kt] = load8bf(W2b + off);
    }
  }
  __syncthreads();

  for (int m = 0; m < 32; ++m) {
    f4v acc[2][2];
#pragma unroll
    for (int mt = 0; mt < 2; ++mt)
#pragma unroll
      for (int nt = 0; nt < 2; ++nt) acc[mt][nt] = (f4v){0.f, 0.f, 0.f, 0.f};
#pragma unroll
    for (int kt = 0; kt < 8; ++kt) {
#pragma unroll
      for (int mt = 0; mt < 2; ++mt) {
        s8v a = __builtin_bit_cast(s8v, *(const uint4*)&hA0[(mt * 16 + l15) * 264 + kt * 32 + q * 8]);
        acc[mt][0] = mfma16(a, w0[0][kt], acc[mt][0]);
        acc[mt][1] = mfma16(a, w0[1][kt], acc[mt][1]);
      }
    }
    __syncthreads();
#pragma unroll
    for (int nt = 0; nt < 2; ++nt) {
      int col = colbase + nt * 16 + l15;
      float wc = w0v[col], bc = b0v[col];
#pragma unroll
      for (int mt = 0; mt < 2; ++mt)
#pragma unroll
        for (int r = 0; r < 4; ++r) {
          int row = mt * 16 + q * 4 + r;
          float v = acc[mt][nt][r] + xe[row] * wc + bc;
          hA0[row * 264 + col] = f2bf(fast_tanh(v));
        }
    }
    __syncthreads();
#pragma unroll
    for (int mt = 0; mt < 2; ++mt)
#pragma unroll
      for (int nt = 0; nt < 2; ++nt) acc[mt][nt] = (f4v){0.f, 0.f, 0.f, 0.f};
#pragma unroll
    for (int kt = 0; kt < 8; ++kt) {
#pragma unroll
      for (int mt = 0; mt < 2; ++mt) {
        s8v a0 = __builtin_bit_cast(s8v, *(const uint4*)&hA0[(mt * 16 + l15) * 264 + kt * 32 + q * 8]);
        s8v a1 = __builtin_bit_cast(s8v, *(const uint4*)&hA1[(mt * 16 + l15) * 264 + kt * 32 + q * 8]);
        acc[mt][0] = mfma16(a0, w1[0][kt], acc[mt][0]);
        acc[mt][1] = mfma16(a0, w1[1][kt], acc[mt][1]);
        acc[mt][0] = mfma16(a1, w2[0][kt], acc[mt][0]);
        acc[mt][1] = mfma16(a1, w2[1][kt], acc[mt][1]);
      }
    }
    __syncthreads();
#pragma unroll
    for (int nt = 0; nt < 2; ++nt) {
      int col = colbase + nt * 16 + l15;
      float bc = b1v[col];
#pragma unroll
      for (int mt = 0; mt < 2; ++mt)
#pragma unroll
        for (int r = 0; r < 4; ++r) {
          int row = mt * 16 + q * 4 + r;
          float v = acc[mt][nt][r] + bc;
          hA1[row * 264 + col] = f2bf(fast_tanh(v));
        }
    }
    __syncthreads();
    if (tid < 256) {
      int row = tid >> 3, seg = tid & 7;
      float sum = 0.f;
#pragma unroll
      for (int u = 0; u < 4; ++u) {
        int col = seg * 32 + u * 8;
#pragma unroll
        for (int e = 0; e < 8; ++e) sum += bf2f(hA1[row * 264 + col + e]) * clsv[col + e];
      }
      sum += __shfl_down(sum, 4, 8);
      sum += __shfl_down(sum, 2, 8);
      sum += __shfl_down(sum, 1, 8);
      if (seg == 0) {
        float pp = fast_sigmoid(sum + clsbs);
        xe[row] = pp;
        Ab[(((size_t)(n0 + row)) << 5) + m] = pp;
      }
    }
    __syncthreads();
  }
}

// ---------------------------------------------------------------------------
// arc_logits[b][j][i] = (j>=max(0,i-32) && j<i) ? Ab[(b*512+i)*32 + j-start] : 0
// ---------------------------------------------------------------------------
__global__ void k_arc(const float* __restrict__ Ab, float* __restrict__ out2) {
  int t = blockIdx.x * 256 + threadIdx.x;  // 4194304 total
  int b = t >> 18;
  int rem = t & 262143;
  int j = rem >> 9, i = rem & 511;
  int start = i - 32;
  if (start < 0) start = 0;
  float v = 0.f;
  if (j >= start && j < i) v = Ab[((((size_t)b << 9) + i) << 5) + (j - start)];
  out2[t] = v;
}

// ---------------------------------------------------------------------------
extern "C" void kernel_launch(void* const* d_in, const int* in_sizes, int n_in,
                              void* d_out, int out_size, void* d_ws, size_t ws_size,
                              hipStream_t stream) {
  const float* input    = (const float*)d_in[0];
  const float* sentinel = (const float*)d_in[1];
  const float* g_Wih0   = (const float*)d_in[2];
  const float* g_Whh0   = (const float*)d_in[3];
  const float* g_bih0   = (const float*)d_in[4];
  const float* g_bhh0   = (const float*)d_in[5];
  const float* g_Wih1   = (const float*)d_in[6];
  const float* g_Whh1   = (const float*)d_in[7];
  const float* g_bih1   = (const float*)d_in[8];
  const float* g_bhh1   = (const float*)d_in[9];
  const float* e_Wih0   = (const float*)d_in[10];
  const float* e_Whh0   = (const float*)d_in[11];
  const float* e_bih0   = (const float*)d_in[12];
  const float* e_bhh0   = (const float*)d_in[13];
  const float* e_Wih1   = (const float*)d_in[14];
  const float* e_Whh1   = (const float*)d_in[15];
  const float* e_bih1   = (const float*)d_in[16];
  const float* e_bhh1   = (const float*)d_in[17];
  const float* cls_W    = (const float*)d_in[18];
  const float* cls_b    = (const float*)d_in[19];
  const float* head_W   = (const float*)d_in[20];
  const float* head_b   = (const float*)d_in[21];
  const float* dep_W    = (const float*)d_in[22];
  const float* dep_b    = (const float*)d_in[23];
  const int* mask       = (const int*)d_in[24];

  float* out = (float*)d_out;
  char* ws = (char*)d_ws;
  float* xw_buf = (float*)ws;                                  // 8 MB
  float* gsb    = (float*)(ws + (16u << 20));                  // 8 MB
  float* Ab     = (float*)(ws + (24u << 20));                  // 1 MB
  size_t o = (25u << 20);
  u16* whh0b   = (u16*)(ws + o); o += 128u << 10;
  u16* whh1b   = (u16*)(ws + o); o += 128u << 10;
  float* maskfb= (float*)(ws + o); o += 32u << 10;
  u16* eb0     = (u16*)(ws + o); o += 128u << 10;
  u16* eb1     = (u16*)(ws + o); o += 128u << 10;
  u16* eb2     = (u16*)(ws + o); o += 128u << 10;
  u16* gw0hi   = (u16*)(ws + o); o += 256u << 10;
  u16* gw0lo   = (u16*)(ws + o); o += 256u << 10;
  u16* gw1hi   = (u16*)(ws + o); o += 128u << 10;
  u16* gw1lo   = (u16*)(ws + o); o += 128u << 10;
  u16* hWhi    = (u16*)(ws + o); o += 64u << 10;
  u16* hWlo    = (u16*)(ws + o); o += 64u << 10;
  u16* dWhi    = (u16*)(ws + o); o += 64u << 10;
  u16* dWlo    = (u16*)(ws + o); o += 64u << 10;

  k_prep<<<2336, 256, 0, stream>>>(g_Whh0, g_Whh1, whh0b, whh1b, e_Whh0, e_Wih1, e_Whh1,
                                   eb0, eb1, eb2, g_Wih0, gw0hi, gw0lo, g_Wih1, gw1hi,
                                   gw1lo, head_W, hWhi, hWlo, dep_W, dWhi, dWlo,
                                   mask, maskfb);
  k_xw0<<<dim3(128, 4), 256, 0, stream>>>(input, sentinel, gw0hi, gw0lo, g_bih0, g_bhh0,
                                          xw_buf);
  k_scan_f<<<16, 512, 0, stream>>>(xw_buf, whh0b, gw1hi, whh1b, g_bih1, g_bhh1,
                                   gsb, maskfb);
  k_gemm<<<dim3(128, 2), 256, 0, stream>>>(gsb, hWhi, hWlo, head_b, nullptr, out,
                                           256, 128, 1);
  k_gemm<<<dim3(128, 2), 256, 0, stream>>>(gsb, dWhi, dWlo, dep_b, nullptr, out + 1048576,
                                           256, 128, 1);
  k_enc<<<256, 512, 0, stream>>>(gsb, eb0, eb1, eb2, e_Wih0, e_bih0, e_bhh0,
                                 e_bih1, e_bhh1, cls_W, cls_b, Ab);
  k_arc<<<16384, 256, 0, stream>>>(Ab, out + 2097152);
}